// Round 5
// baseline (331.367 us; speedup 1.0000x reference)
//
#include <hip/hip_runtime.h>
#include <hip/hip_fp16.h>
#include <cstdint>
#include <cstddef>

// ---------------------------------------------------------------------------
// VectorQuantizerEMA on MI355X.  B=8,S=2048,D=256,K=4096 -> N=16384 tokens.
// R4 design: SINGLE fp16 GEMM (h1.b1) for approximate distances + rigorous
// error bound + exact fp64 rescore of the few candidates per token.
//   1) split z / codebook to fp16 h1 rows (512B) + residual norms (x2048);
//      codebook also: fp32 |c|^2, global max residual/b1 norms (atomicMax)
//   2) vq_gemm: 128x128 tile, 4 waves, BK=32, dbuf LDS 2x16KB, 3 blocks/CU;
//      epilogue keeps top-2 (value,index) per 64-entry slot -> 64 slots/token
//   3) vq_merge: global approx min; candidates within min+2E+slack; exact
//      fp64 rescore; gather codebook row -> out; loss partials; scatter n/dw
//   4) new_weight elementwise; new_count normalize + loss finalize
// R1: removed same-address atomic chains. R2: dbuf pipeline (177us, util 25%).
// R3: counted-vmcnt 8-wave: REGRESSED (266MB fetch, util still 23%) ->
//     schedule is not the lever; total pipe work is. R4 cuts MFMA+LDS 3x.
// ---------------------------------------------------------------------------

#define N_TOK 16384
#define DIM   256
#define K_CB  4096

typedef _Float16 h8    __attribute__((ext_vector_type(8)));
typedef float    f32x4 __attribute__((ext_vector_type(4)));

// ---- ws layout (bytes) ----
#define WS_ZP1     0u            // N_TOK * 512B fp16 rows      = 8 MB
#define WS_CP1     8388608u      // K_CB  * 512B fp16 rows      = 2 MB
#define WS_CN1     10485760u     // K_CB fp32 |c|^2             = 16 KB
#define WS_NRM     10502144u     // N_TOK float2 (|h1|,|e_z|*2048) = 128 KB
#define WS_CANDV   10630144u     // N_TOK * 64 float2           = 8 MB
#define WS_CANDI   19018752u     // N_TOK * 64 int2             = 8 MB
#define WS_DW      27407360u     // K_CB * DIM float            = 4 MB
#define WS_NACC    31601664u     // K_CB float                  = 16 KB
#define WS_NB      31618048u     // 2 floats: max|b1|, max|e_c|*2048
#define WS_LPART   31618112u     // 4096 float
#define WS_MPART   31634496u     // 4096 float
#define WS_ZERO_BYTES 4210704u   // DW + NACC + NB contiguous

__device__ __forceinline__ void gload_lds16(const void* g, void* l) {
  __builtin_amdgcn_global_load_lds(
      (const __attribute__((address_space(1))) uint32_t*)g,
      (__attribute__((address_space(3))) uint32_t*)l, 16, 0, 0);
}

// ---- 1a: split z -> h1 rows + (|h1|, |residual*2048|) per token ------------
__global__ void vq_split_z(const float* __restrict__ z, unsigned short* __restrict__ zp1,
                           float2* __restrict__ nrm) {
  int tid = blockIdx.x * 256 + threadIdx.x;       // wave (64 lanes) = one row
  int row = tid >> 6, c4 = tid & 63;
  float4 v = reinterpret_cast<const float4*>(z)[tid];
  float x[4] = {v.x, v.y, v.z, v.w};
  union { _Float16 h[4]; ushort4 u; } a;
  float s1 = 0.f, s2 = 0.f;
#pragma unroll
  for (int i = 0; i < 4; ++i) {
    _Float16 h1 = (_Float16)x[i];
    float lo = (x[i] - (float)h1) * 2048.0f;
    a.h[i] = h1;
    s1 += (float)h1 * (float)h1;
    s2 += lo * lo;
  }
  reinterpret_cast<ushort4*>(zp1)[row * 64 + c4] = a.u;
  for (int off = 1; off < 64; off <<= 1) { s1 += __shfl_xor(s1, off); s2 += __shfl_xor(s2, off); }
  if (c4 == 0) nrm[row] = make_float2(sqrtf(s1), sqrtf(s2));
}

// ---- 1b: split codebook -> h1 rows + fp32 |c|^2 + global max norms ---------
__global__ void vq_split_c(const float* __restrict__ cb, unsigned short* __restrict__ cp1,
                           float* __restrict__ cn1, float* __restrict__ nb) {
  int w = threadIdx.x >> 6, l = threadIdx.x & 63;
  int row = blockIdx.x * 4 + w;
  float4 v = reinterpret_cast<const float4*>(cb)[row * 64 + l];
  float x[4] = {v.x, v.y, v.z, v.w};
  union { _Float16 h[4]; ushort4 u; } a;
  double ss = 0.0;
  float s1 = 0.f, s2 = 0.f;
#pragma unroll
  for (int i = 0; i < 4; ++i) {
    _Float16 h1 = (_Float16)x[i];
    float lo = (x[i] - (float)h1) * 2048.0f;
    a.h[i] = h1;
    s1 += (float)h1 * (float)h1;
    s2 += lo * lo;
    ss += (double)x[i] * (double)x[i];
  }
  reinterpret_cast<ushort4*>(cp1)[row * 64 + l] = a.u;
  for (int off = 1; off < 64; off <<= 1) {
    s1 += __shfl_xor(s1, off); s2 += __shfl_xor(s2, off); ss += __shfl_xor(ss, off);
  }
  if (l == 0) {
    cn1[row] = (float)ss;
    atomicMax((int*)&nb[0], __float_as_int(sqrtf(s1)));   // positive floats: int order ok
    atomicMax((int*)&nb[1], __float_as_int(sqrtf(s2)));
  }
}

// ---- 2: approx distance GEMM + top-2 per 64-entry slot ---------------------
// 256 thr = 4 waves (2x2). Tile 128 tokens x 128 entries, BK=32 dims.
// LDS buffer 16KB: A 128 rows x 64B | B 128 rows x 64B; row = 4 chunks of
// 16B, stored chunk = logical ^ (row&3) (swizzle on global SOURCE address;
// global_load_lds writes linearly, per-wave 1KB regions). Double-buffered.
__global__ __launch_bounds__(256, 3) void vq_gemm(
    const unsigned short* __restrict__ zp1, const unsigned short* __restrict__ cp1,
    const float* __restrict__ cn1,
    float2* __restrict__ cand_v, int2* __restrict__ cand_i) {
  __shared__ __align__(1024) unsigned char lds[32768];   // 2 x (A 8KB | B 8KB)

  // XCD-aware bijective swizzle (R2's, fetch-verified 24.8MB)
  const int bid = blockIdx.x;
  const int wg  = (bid & 7) * 512 + (bid >> 3);
  const int mb  = (wg >> 9) * 16 + (wg & 15);   // 0..127
  const int nb  = (wg >> 4) & 31;               // 0..31
  const int token0 = mb * 128, entry0 = nb * 128;

  const int tx = threadIdx.x;
  const int w  = tx >> 6, l = tx & 63;
  const int waveM = w >> 1, waveN = w & 1;
  const int fr = l & 15, fk = l >> 4;

  // staging: 4 gload calls/tile; wave w, lane l fills LDS j*4096 + w*1024 + l*16
  // -> row = j*64 + w*16 + (l>>2), stored chunk = l&3, logical = (l&3)^(row&3)
  const int rloc = w * 16 + (l >> 2);
  const int lc   = (l & 3) ^ ((l >> 2) & 3);    // w*16 = 0 mod 4
  const unsigned char* zb  = (const unsigned char*)zp1;
  const unsigned char* cbp = (const unsigned char*)cp1;
  const unsigned char* srcA[2]; const unsigned char* srcB[2];
  unsigned dA[2], dB[2];
#pragma unroll
  for (int j = 0; j < 2; ++j) {
    srcA[j] = zb  + (size_t)(token0 + j * 64 + rloc) * 512 + lc * 16;
    srcB[j] = cbp + (size_t)(entry0 + j * 64 + rloc) * 512 + lc * 16;
    dA[j] = (unsigned)(j * 4096 + w * 1024);
    dB[j] = 8192u + (unsigned)(j * 4096 + w * 1024);
  }

  f32x4 zero = {0.f, 0.f, 0.f, 0.f};
  f32x4 acc[4][4];
#pragma unroll
  for (int m = 0; m < 4; ++m)
#pragma unroll
    for (int n = 0; n < 4; ++n) acc[m][n] = zero;

  // prologue: stage tile 0 into buffer 0
#pragma unroll
  for (int j = 0; j < 2; ++j) {
    gload_lds16(srcA[j], &lds[dA[j]]);
    gload_lds16(srcB[j], &lds[dB[j]]);
  }
  __syncthreads();

  unsigned cur = 0;
  for (int t = 0; t < 8; ++t) {
    if (t < 7) {                      // stage t+1 into other buffer first
      unsigned off = (cur ^ 1) * 16384u;
#pragma unroll
      for (int j = 0; j < 2; ++j) {
        gload_lds16(srcA[j] + (t + 1) * 64, &lds[off + dA[j]]);
        gload_lds16(srcB[j] + (t + 1) * 64, &lds[off + dB[j]]);
      }
    }

    const unsigned char* la = &lds[cur * 16384u];
    const unsigned char* lb = la + 8192;
    h8 af[4], bf[4];
#pragma unroll
    for (int m = 0; m < 4; ++m) {
      int r = waveM * 64 + m * 16 + fr;
      af[m] = *(const h8*)&la[r * 64 + ((fk ^ (r & 3)) * 16)];
    }
#pragma unroll
    for (int n = 0; n < 4; ++n) {
      int r = waveN * 64 + n * 16 + fr;
      bf[n] = *(const h8*)&lb[r * 64 + ((fk ^ (r & 3)) * 16)];
    }

    __builtin_amdgcn_s_setprio(1);
#pragma unroll
    for (int m = 0; m < 4; ++m)
#pragma unroll
      for (int n = 0; n < 4; ++n)
        acc[m][n] = __builtin_amdgcn_mfma_f32_16x16x32_f16(af[m], bf[n], acc[m][n], 0, 0, 0);
    __builtin_amdgcn_s_setprio(0);

    if (t < 7) {
      __syncthreads();
      cur ^= 1;
    }
  }

  // epilogue: d_approx = |c|^2 - 2*acc (fp32); top-2 per slot (64 entries)
  float cn[4];
#pragma unroll
  for (int n = 0; n < 4; ++n) cn[n] = cn1[entry0 + waveN * 64 + n * 16 + fr];

#define INS2(d, e)                                            \
  do {                                                        \
    float _d = (d); int _e = (e);                             \
    if (_d < v1 || (_d == v1 && _e < i1)) {                   \
      v2 = v1; i2 = i1; v1 = _d; i1 = _e;                     \
    } else if (_d < v2 || (_d == v2 && _e < i2)) {            \
      v2 = _d; i2 = _e;                                       \
    }                                                         \
  } while (0)

#pragma unroll
  for (int m = 0; m < 4; ++m) {
#pragma unroll
    for (int rI = 0; rI < 4; ++rI) {
      float v1 = 3e38f, v2 = 3e38f; int i1 = 0x7fffffff, i2 = 0x7fffffff;
#pragma unroll
      for (int n = 0; n < 4; ++n) {
        float d = cn[n] - 2.0f * acc[m][n][rI];
        INS2(d, entry0 + waveN * 64 + n * 16 + fr);
      }
#pragma unroll
      for (int off = 1; off < 16; off <<= 1) {   // across 16 fragment cols
        float ov1 = __shfl_xor(v1, off), ov2 = __shfl_xor(v2, off);
        int   oi1 = __shfl_xor(i1, off), oi2 = __shfl_xor(i2, off);
        INS2(ov1, oi1);
        INS2(ov2, oi2);
      }
      if (fr == 0) {
        int token = token0 + waveM * 64 + m * 16 + fk * 4 + rI;
        int slot  = nb * 2 + waveN;              // 64 slots per token
        cand_v[(size_t)token * 64 + slot] = make_float2(v1, v2);
        cand_i[(size_t)token * 64 + slot] = make_int2(i1, i2);
      }
    }
  }
#undef INS2
}

// ---- 3: candidate filter + exact fp64 rescore; out/loss; scatter n/dw ------
__global__ void vq_merge_scatter(
    const float2* __restrict__ cand_v, const int2* __restrict__ cand_i,
    const float* __restrict__ z, const float* __restrict__ mask,
    const float* __restrict__ codebook,
    const float2* __restrict__ nrm, const float* __restrict__ nb,
    float* __restrict__ out0, float* __restrict__ out_idx,
    float* __restrict__ dw, float* __restrict__ nacc,
    float* __restrict__ loss_part, float* __restrict__ mask_part) {
  __shared__ float ls[4], ms[4];
  int w = threadIdx.x >> 6, l = threadIdx.x & 63;
  int token = blockIdx.x * 4 + w;

  float2 v  = cand_v[(size_t)token * 64 + l];
  int2   id = cand_i[(size_t)token * 64 + l];
  float m_a = v.x;
  for (int off = 1; off < 64; off <<= 1) m_a = fminf(m_a, __shfl_xor(m_a, off));

  // rigorous error bound: z.c - h1.b1 = h1.e_c + e_z.b1 + e_z.e_c (scaled)
  float2 nh = nrm[token];
  float NB1 = nb[0], NB2 = nb[1];
  float E = 2.0f * ((nh.x * NB2 + nh.y * NB1) * (1.0f / 2048.0f)
                    + nh.y * NB2 * (1.0f / 4194304.0f));
  float thresh = m_a + 2.0f * E * 1.05f + 0.05f;   // + fp32 pipeline slack

  float4 zv = reinterpret_cast<const float4*>(z)[(size_t)token * 64 + l];

  unsigned long long c1 = __ballot(v.x <= thresh);
  unsigned long long c2 = __ballot(v.y <= thresh);
  double bd = 1e300; int bi = 0x7fffffff;
  while (c1 | c2) {
    int k;
    if (c1) { int s = __ffsll((unsigned long long)c1) - 1; c1 &= c1 - 1; k = __shfl(id.x, s); }
    else    { int s = __ffsll((unsigned long long)c2) - 1; c2 &= c2 - 1; k = __shfl(id.y, s); }
    float4 cv = reinterpret_cast<const float4*>(codebook)[(size_t)k * 64 + l];
    double d0 = (double)zv.x - cv.x, d1 = (double)zv.y - cv.y;
    double d2 = (double)zv.z - cv.z, d3 = (double)zv.w - cv.w;
    double dd = d0 * d0 + d1 * d1 + d2 * d2 + d3 * d3;
    for (int off = 1; off < 64; off <<= 1) dd += __shfl_xor(dd, off);
    if (dd < bd || (dd == bd && k < bi)) { bd = dd; bi = k; }
  }

  float4 cv = reinterpret_cast<const float4*>(codebook)[(size_t)bi * 64 + l];
  reinterpret_cast<float4*>(out0)[(size_t)token * 64 + l] = cv;   // out == quantized

  float mk = mask[token];
  if (l == 0) {
    out_idx[token] = (float)bi;
    ls[w] = mk * (float)bd * (1.0f / 256.0f);   // bd = sum (z-q)^2 exactly
    ms[w] = mk;
    atomicAdd(&nacc[bi], mk);
  }
  if (mk != 0.0f) {
    float* p = dw + (size_t)bi * 256 + l * 4;
    atomicAdd(p + 0, mk * zv.x);
    atomicAdd(p + 1, mk * zv.y);
    atomicAdd(p + 2, mk * zv.z);
    atomicAdd(p + 3, mk * zv.w);
  }
  __syncthreads();
  if (threadIdx.x == 0) {
    loss_part[blockIdx.x] = ls[0] + ls[1] + ls[2] + ls[3];
    mask_part[blockIdx.x] = ms[0] + ms[1] + ms[2] + ms[3];
  }
}

// ---- 4a: new_weight --------------------------------------------------------
__global__ void vq_finish_weight(const float* __restrict__ ew, const float* __restrict__ dw,
                                 float* __restrict__ nw) {
  int i = blockIdx.x * 256 + threadIdx.x;       // over K*D/4
  float4 e = reinterpret_cast<const float4*>(ew)[i];
  float4 d = reinterpret_cast<const float4*>(dw)[i];
  float4 o;
  o.x = 0.99f * e.x + 0.01f * d.x;
  o.y = 0.99f * e.y + 0.01f * d.y;
  o.z = 0.99f * e.z + 0.01f * d.z;
  o.w = 0.99f * e.w + 0.01f * d.w;
  reinterpret_cast<float4*>(nw)[i] = o;
}

// ---- 4b: new_count normalize + deterministic loss reduce -------------------
__global__ void vq_finish_count(const float* __restrict__ ec, const float* __restrict__ nacc,
                                const float* __restrict__ loss_part,
                                const float* __restrict__ mask_part,
                                float* __restrict__ out_count, float* __restrict__ out_loss) {
  __shared__ float nc_s[K_CB];
  __shared__ float red[256];
  int tid = threadIdx.x;
  float part = 0.f;
  for (int i = tid; i < K_CB; i += 256) {
    float nc = 0.99f * ec[i] + 0.01f * nacc[i];
    nc_s[i] = nc; part += nc;
  }
  red[tid] = part; __syncthreads();
  for (int s = 128; s > 0; s >>= 1) { if (tid < s) red[tid] += red[tid + s]; __syncthreads(); }
  float total = red[0];
  float scale = total / (total + (float)K_CB * 1e-5f);
  for (int i = tid; i < K_CB; i += 256) out_count[i] = (nc_s[i] + 1e-5f) * scale;
  __syncthreads();

  float ln = 0.f, lm = 0.f;
  for (int i = tid; i < 4096; i += 256) { ln += loss_part[i]; lm += mask_part[i]; }
  red[tid] = ln; __syncthreads();
  for (int s = 128; s > 0; s >>= 1) { if (tid < s) red[tid] += red[tid + s]; __syncthreads(); }
  ln = red[0]; __syncthreads();
  red[tid] = lm; __syncthreads();
  for (int s = 128; s > 0; s >>= 1) { if (tid < s) red[tid] += red[tid + s]; __syncthreads(); }
  lm = red[0];
  if (tid == 0) out_loss[0] = 2.5f * ln / lm;   // 10 * 0.25 * num/den
}

extern "C" void kernel_launch(void* const* d_in, const int* in_sizes, int n_in,
                              void* d_out, int out_size, void* d_ws, size_t ws_size,
                              hipStream_t stream) {
  const float* z          = (const float*)d_in[0];
  const float* mask       = (const float*)d_in[1];
  const float* codebook   = (const float*)d_in[2];
  const float* ema_count  = (const float*)d_in[3];
  const float* ema_weight = (const float*)d_in[4];

  float* out        = (float*)d_out;
  float* out0       = out;                         // 4194304
  float* out_idx    = out + 4194304;               // 16384
  float* out_loss   = out + 4210688;               // 1
  float* out_count  = out + 4210689;               // 4096
  float* out_weight = out + 4214785;               // 1048576

  char* ws = (char*)d_ws;
  unsigned short* zp1 = (unsigned short*)(ws + WS_ZP1);
  unsigned short* cp1 = (unsigned short*)(ws + WS_CP1);
  float*  cn1     = (float*) (ws + WS_CN1);
  float2* nrm     = (float2*)(ws + WS_NRM);
  float2* cand_v  = (float2*)(ws + WS_CANDV);
  int2*   cand_i  = (int2*)  (ws + WS_CANDI);
  float*  dw      = (float*) (ws + WS_DW);
  float*  nacc    = (float*) (ws + WS_NACC);
  float*  nbmax   = (float*) (ws + WS_NB);
  float*  lpart   = (float*) (ws + WS_LPART);
  float*  mpart   = (float*) (ws + WS_MPART);

  (void)hipMemsetAsync(ws + WS_DW, 0, WS_ZERO_BYTES, stream);

  vq_split_z<<<4096, 256, 0, stream>>>(z, zp1, nrm);
  vq_split_c<<<1024, 256, 0, stream>>>(codebook, cp1, cn1, nbmax);
  vq_gemm<<<4096, 256, 0, stream>>>(zp1, cp1, cn1, cand_v, cand_i);
  vq_merge_scatter<<<4096, 256, 0, stream>>>(cand_v, cand_i, z, mask, codebook,
                                             nrm, nbmax, out0, out_idx, dw, nacc,
                                             lpart, mpart);
  vq_finish_weight<<<1024, 256, 0, stream>>>(ema_weight, dw, out_weight);
  vq_finish_count<<<1, 256, 0, stream>>>(ema_count, nacc, lpart, mpart,
                                         out_count, out_loss);
}

// Round 6
// 255.673 us; speedup vs baseline: 1.2961x; 1.2961x over previous
//
#include <hip/hip_runtime.h>
#include <hip/hip_fp16.h>
#include <cstdint>
#include <cstddef>

// ---------------------------------------------------------------------------
// VectorQuantizerEMA on MI355X.  B=8,S=2048,D=256,K=4096 -> N=16384 tokens.
// R5 design: 32x32x16 MFMA scan with Z register-resident.
//   1) split z -> fp16 h1 fragments (B-operand layout) + per-token norms;
//      split codebook -> fp16 h1 rows + fp32 |c|^2 + global max norms
//   2) vq_scan: grid = 128 token-groups x 8 entry-splits. Per block: 4 waves,
//      each wave owns 32 tokens (Z in 64 VGPRs), codebook streams via 16KB
//      dbuf LDS tiles (XOR-32 swizzle, staged with pre-swizzled global src).
//      Per 32-entry tile: 16 ds_read_b128 + 16 mfma_32x32x16_f16 (1KB LDS per
//      32768 FLOP) + per-lane running top-2 (no cross-lane work until end).
//      Output: 1 record (top-2 val+idx) per token per split -> 2MB total.
//   3) vq_merge: min over 8 records, window = rigorous error bound, exact
//      fp64 rescore of windowed candidates; gather row -> out; loss partials;
//      distributed atomic scatter n/dw
//   4) new_weight elementwise; new_count normalize + loss finalize
// History: R1 removed same-address atomic chains (429us). R2 dbuf (177us,
// util 25%). R3 counted-vmcnt 8-wave: regressed. R4 1-GEMM+rescore: gemm
// 135us but VALU-bound epilogue (58%) + 4-way LDS conflicts + 16MB cand
// arrays made merge ~150us. R5 attacks all three structurally.
// ---------------------------------------------------------------------------

#define N_TOK 16384
#define DIM   256
#define K_CB  4096

typedef _Float16 h8    __attribute__((ext_vector_type(8)));
typedef float    f32x4 __attribute__((ext_vector_type(4)));
typedef float    f32x16 __attribute__((ext_vector_type(16)));

// ---- ws layout (bytes) ----
#define WS_ZF      0u            // N_TOK * 512B fp16 frag layout = 8 MB
#define WS_CP      8388608u      // K_CB * 512B fp16 rows         = 2 MB
#define WS_CN      10485760u     // K_CB fp32 |c|^2               = 16 KB
#define WS_NRM     10502144u     // N_TOK float2                  = 128 KB
#define WS_CAND    10630144u     // N_TOK * 8 float4              = 2 MB
#define WS_DW      12727296u     // K_CB * DIM float              = 4 MB
#define WS_NACC    16921600u     // K_CB float                    = 16 KB
#define WS_NB      16937984u     // 2 floats (+pad 16B)
#define WS_LPART   16938000u     // 4096 float
#define WS_MPART   16954384u     // 4096 float
#define WS_ZERO_BYTES (4194304u + 16384u + 16u)   // DW + NACC + NB

__device__ __forceinline__ void gload_lds16(const void* g, void* l) {
  __builtin_amdgcn_global_load_lds(
      (const __attribute__((address_space(1))) uint32_t*)g,
      (__attribute__((address_space(3))) uint32_t*)l, 16, 0, 0);
}

// ---- 1a: split z -> fragment-layout fp16 + per-token norms -----------------
// zf layout: grp(tok>>7)*65536 + kt*4096 + (tok&127)*32 + h*16 bytes; chunk
// (kt,h) holds dims kt*16+h*8 .. +8 as 8 halves. This makes the scan's
// B-operand loads perfectly coalesced (1KB per wave instruction).
__global__ void vq_split_z(const float* __restrict__ z, unsigned short* __restrict__ zf,
                           float2* __restrict__ nrm) {
  int t = blockIdx.x * 256 + threadIdx.x;       // 524288 threads, 32 per token
  int tok = t >> 5, c = t & 31;
  const float4* zp = reinterpret_cast<const float4*>(z) + (size_t)tok * 64 + c * 2;
  float4 va = zp[0], vb = zp[1];
  float x[8] = {va.x, va.y, va.z, va.w, vb.x, vb.y, vb.z, vb.w};
  union { _Float16 h[8]; uint4 u; } a;
  float s1 = 0.f, s2 = 0.f;
#pragma unroll
  for (int i = 0; i < 8; ++i) {
    _Float16 h1 = (_Float16)x[i];
    float lo = (x[i] - (float)h1) * 2048.0f;
    a.h[i] = h1;
    s1 += (float)h1 * (float)h1;
    s2 += lo * lo;
  }
  size_t off = (size_t)(tok >> 7) * 65536u + (size_t)(c >> 1) * 4096u
             + (size_t)(tok & 127) * 32u + (size_t)(c & 1) * 16u;
  *reinterpret_cast<uint4*>((unsigned char*)zf + off) = a.u;
#pragma unroll
  for (int o = 1; o < 32; o <<= 1) { s1 += __shfl_xor(s1, o); s2 += __shfl_xor(s2, o); }
  if (c == 0) nrm[tok] = make_float2(sqrtf(s1), sqrtf(s2));
}

// ---- 1b: split codebook -> h1 rows (512B row-major) + |c|^2 + max norms ----
__global__ void vq_split_c(const float* __restrict__ cb, unsigned short* __restrict__ cp1,
                           float* __restrict__ cn1, float* __restrict__ nb) {
  int w = threadIdx.x >> 6, l = threadIdx.x & 63;
  int row = blockIdx.x * 4 + w;
  float4 v = reinterpret_cast<const float4*>(cb)[row * 64 + l];
  float x[4] = {v.x, v.y, v.z, v.w};
  union { _Float16 h[4]; ushort4 u; } a;
  double ss = 0.0;
  float s1 = 0.f, s2 = 0.f;
#pragma unroll
  for (int i = 0; i < 4; ++i) {
    _Float16 h1 = (_Float16)x[i];
    float lo = (x[i] - (float)h1) * 2048.0f;
    a.h[i] = h1;
    s1 += (float)h1 * (float)h1;
    s2 += lo * lo;
    ss += (double)x[i] * (double)x[i];
  }
  reinterpret_cast<ushort4*>(cp1)[row * 64 + l] = a.u;
  for (int off = 1; off < 64; off <<= 1) {
    s1 += __shfl_xor(s1, off); s2 += __shfl_xor(s2, off); ss += __shfl_xor(ss, off);
  }
  if (l == 0) {
    cn1[row] = (float)ss;
    atomicMax((int*)&nb[0], __float_as_int(sqrtf(s1)));   // positive floats
    atomicMax((int*)&nb[1], __float_as_int(sqrtf(s2)));
  }
}

// ---- 2: distance scan, 32x32x16 MFMA, per-lane running top-2 ---------------
// Grid 1024 = 128 token-groups x 8 entry-splits (XCD-swizzled). 4 waves/block,
// wave w owns tokens tok0+w*32..+31 (Z frags in 64 VGPRs). CB tile = 32
// entries x 512B in LDS, dbuf. LDS chunk swizzle: stored chunk = logical ^
// (row&31) applied on the global SOURCE (gload_lds writes linearly).
// D = A(CB) x B(Z): D[row=entry][col=token]; col=lane&31,
// row=(reg&3)+8*(reg>>2)+4*(lane>>5).
__global__ __launch_bounds__(256, 4) void vq_scan(
    const unsigned short* __restrict__ zf, const unsigned short* __restrict__ cp,
    const float* __restrict__ cn1, float4* __restrict__ cand) {
  __shared__ __align__(1024) unsigned char cbl[2][16384];
  __shared__ __align__(16) float cnl[2][32];

  const int bid  = blockIdx.x;
  const int wgid = (bid & 7) * 128 + (bid >> 3);   // bijective: 1024 = 8*128
  const int tg   = wgid >> 3;                      // 0..127 token group
  const int es   = wgid & 7;                       // 0..7 entry split
  const int tok0 = tg * 128;
  const int e0b  = es * 512;

  const int tx = threadIdx.x;
  const int w = tx >> 6, l = tx & 63;
  const int r = l & 31, h = l >> 5;

  // Z fragments (B-operand): 16 x h8 = 64 VGPRs, coalesced 1KB loads
  const unsigned char* zg = (const unsigned char*)zf + (size_t)tg * 65536u
                            + (unsigned)(w * 1024 + r * 32 + h * 16);
  h8 zfr[16];
#pragma unroll
  for (int kt = 0; kt < 16; ++kt)
    zfr[kt] = *reinterpret_cast<const h8*>(zg + kt * 4096);

  const unsigned char* cpb = (const unsigned char*)cp;

  float v1 = 3e38f, v2 = 3e38f;
  int   i1 = 0x7fffffff, i2 = 0x7fffffff;

  // prologue: stage tile 0 into buffer 0
#pragma unroll
  for (int j = 0; j < 4; ++j) {
    int row = (w * 4 + j) * 2 + h;                 // 0..31, each once
    int lc  = r ^ row;                             // logical chunk to fetch
    gload_lds16(cpb + (size_t)(e0b + row) * 512 + lc * 16,
                &cbl[0][(w * 4 + j) * 1024]);      // wave-uniform dst
  }
  if (tx < 8)
    gload_lds16((const unsigned char*)cn1 + (size_t)e0b * 4 + tx * 16, &cnl[0][0]);
  __syncthreads();

  for (int t = 0; t < 16; ++t) {
    const int b = t & 1;
    if (t < 15) {                                  // stage t+1 first
      const int e0n = e0b + (t + 1) * 32;
#pragma unroll
      for (int j = 0; j < 4; ++j) {
        int row = (w * 4 + j) * 2 + h;
        int lc  = r ^ row;
        gload_lds16(cpb + (size_t)(e0n + row) * 512 + lc * 16,
                    &cbl[b ^ 1][(w * 4 + j) * 1024]);
      }
      if (tx < 8)
        gload_lds16((const unsigned char*)cn1 + (size_t)e0n * 4 + tx * 16,
                    &cnl[b ^ 1][0]);
    }

    f32x16 acc;
#pragma unroll
    for (int i = 0; i < 16; ++i) acc[i] = 0.f;
#pragma unroll
    for (int kt = 0; kt < 16; ++kt) {
      int sc = (kt * 2 + h) ^ r;                   // swizzled chunk
      h8 af = *reinterpret_cast<const h8*>(&cbl[b][r * 512 + sc * 16]);
      acc = __builtin_amdgcn_mfma_f32_32x32x16_f16(af, zfr[kt], acc, 0, 0, 0);
    }

    const int e0 = e0b + t * 32 + 4 * h;
#pragma unroll
    for (int g = 0; g < 4; ++g) {
      f32x4 cnv = *reinterpret_cast<const f32x4*>(&cnl[b][g * 8 + 4 * h]);
#pragma unroll
      for (int q = 0; q < 4; ++q) {
        float d = cnv[q] - 2.0f * acc[g * 4 + q];
        int   e = e0 + g * 8 + q;
        bool c1 = d < v1, c2 = d < v2;
        i2 = c1 ? i1 : (c2 ? e : i2);
        v2 = c1 ? v1 : (c2 ? d : v2);
        i1 = c1 ? e : i1;
        v1 = c1 ? d : v1;
      }
    }
    __syncthreads();
  }

  // merge the two lane-halves (entries 4h split), then write one record
  {
    float ov1 = __shfl_xor(v1, 32), ov2 = __shfl_xor(v2, 32);
    int   oi1 = __shfl_xor(i1, 32), oi2 = __shfl_xor(i2, 32);
    if (ov1 < v1 || (ov1 == v1 && oi1 < i1)) {
      v2 = v1; i2 = i1; v1 = ov1; i1 = oi1;
    } else if (ov1 < v2 || (ov1 == v2 && oi1 < i2)) {
      v2 = ov1; i2 = oi1;
    }
    if (ov2 < v1 || (ov2 == v1 && oi2 < i1)) {
      v2 = v1; i2 = i1; v1 = ov2; i1 = oi2;
    } else if (ov2 < v2 || (ov2 == v2 && oi2 < i2)) {
      v2 = ov2; i2 = oi2;
    }
    if (h == 0) {
      int token = tok0 + w * 32 + r;
      cand[(size_t)token * 8 + es] =
          make_float4(v1, v2, __int_as_float(i1), __int_as_float(i2));
    }
  }
}

// ---- 3: window + exact fp64 rescore; out/loss; scatter n/dw ----------------
__global__ void vq_merge_scatter(
    const float4* __restrict__ cand, const float* __restrict__ z,
    const float* __restrict__ mask, const float* __restrict__ codebook,
    const float2* __restrict__ nrm, const float* __restrict__ nb,
    float* __restrict__ out0, float* __restrict__ out_idx,
    float* __restrict__ dw, float* __restrict__ nacc,
    float* __restrict__ loss_part, float* __restrict__ mask_part) {
  __shared__ float ls[4], ms[4];
  int w = threadIdx.x >> 6, l = threadIdx.x & 63;
  int token = blockIdx.x * 4 + w;

  float4 rec = cand[(size_t)token * 8 + (l & 7)];  // 8 records, replicated x8
  float rv1 = rec.x, rv2 = rec.y;
  int   ri1 = __float_as_int(rec.z), ri2 = __float_as_int(rec.w);
  float m_a = rv1;
  for (int o = 1; o < 8; o <<= 1) m_a = fminf(m_a, __shfl_xor(m_a, o));

  // rigorous error bound: z.c - h1.b1 = h1.e_c + e_z.b1 + e_z.e_c (scaled)
  float2 nh = nrm[token];
  float NB1 = nb[0], NB2 = nb[1];
  float E = 2.0f * ((nh.x * NB2 + nh.y * NB1) * (1.0f / 2048.0f)
                    + nh.y * NB2 * (1.0f / 4194304.0f));
  float thr = m_a + 2.0f * E * 1.05f + 0.05f;

  float4 zv = reinterpret_cast<const float4*>(z)[(size_t)token * 64 + l];

  unsigned long long c1 = __ballot((l < 8) && (rv1 <= thr));
  unsigned long long c2 = __ballot((l < 8) && (rv2 <= thr));
  double bd = 1e300; int bi = 0x7fffffff;
  while (c1 | c2) {
    int k;
    if (c1) { int s = __ffsll(c1) - 1; c1 &= c1 - 1; k = __shfl(ri1, s); }
    else    { int s = __ffsll(c2) - 1; c2 &= c2 - 1; k = __shfl(ri2, s); }
    float4 cv = reinterpret_cast<const float4*>(codebook)[(size_t)k * 64 + l];
    double d0 = (double)zv.x - cv.x, d1 = (double)zv.y - cv.y;
    double d2 = (double)zv.z - cv.z, d3 = (double)zv.w - cv.w;
    double dd = d0 * d0 + d1 * d1 + d2 * d2 + d3 * d3;
    for (int o = 1; o < 64; o <<= 1) dd += __shfl_xor(dd, o);
    if (dd < bd || (dd == bd && k < bi)) { bd = dd; bi = k; }
  }

  float4 cv = reinterpret_cast<const float4*>(codebook)[(size_t)bi * 64 + l];
  reinterpret_cast<float4*>(out0)[(size_t)token * 64 + l] = cv;   // quantized

  float mk = mask[token];
  if (l == 0) {
    out_idx[token] = (float)bi;
    ls[w] = mk * (float)bd * (1.0f / 256.0f);      // exact sum (z-q)^2
    ms[w] = mk;
    atomicAdd(&nacc[bi], mk);
  }
  if (mk != 0.0f) {
    float* p = dw + (size_t)bi * 256 + l * 4;
    atomicAdd(p + 0, mk * zv.x);
    atomicAdd(p + 1, mk * zv.y);
    atomicAdd(p + 2, mk * zv.z);
    atomicAdd(p + 3, mk * zv.w);
  }
  __syncthreads();
  if (threadIdx.x == 0) {
    loss_part[blockIdx.x] = ls[0] + ls[1] + ls[2] + ls[3];
    mask_part[blockIdx.x] = ms[0] + ms[1] + ms[2] + ms[3];
  }
}

// ---- 4a: new_weight --------------------------------------------------------
__global__ void vq_finish_weight(const float* __restrict__ ew, const float* __restrict__ dw,
                                 float* __restrict__ nw) {
  int i = blockIdx.x * 256 + threadIdx.x;          // over K*D/4
  float4 e = reinterpret_cast<const float4*>(ew)[i];
  float4 d = reinterpret_cast<const float4*>(dw)[i];
  float4 o;
  o.x = 0.99f * e.x + 0.01f * d.x;
  o.y = 0.99f * e.y + 0.01f * d.y;
  o.z = 0.99f * e.z + 0.01f * d.z;
  o.w = 0.99f * e.w + 0.01f * d.w;
  reinterpret_cast<float4*>(nw)[i] = o;
}

// ---- 4b: new_count normalize + deterministic loss reduce -------------------
__global__ void vq_finish_count(const float* __restrict__ ec, const float* __restrict__ nacc,
                                const float* __restrict__ loss_part,
                                const float* __restrict__ mask_part,
                                float* __restrict__ out_count, float* __restrict__ out_loss) {
  __shared__ float nc_s[K_CB];
  __shared__ float red[256];
  int tid = threadIdx.x;
  float part = 0.f;
  for (int i = tid; i < K_CB; i += 256) {
    float nc = 0.99f * ec[i] + 0.01f * nacc[i];
    nc_s[i] = nc; part += nc;
  }
  red[tid] = part; __syncthreads();
  for (int s = 128; s > 0; s >>= 1) { if (tid < s) red[tid] += red[tid + s]; __syncthreads(); }
  float total = red[0];
  float scale = total / (total + (float)K_CB * 1e-5f);
  for (int i = tid; i < K_CB; i += 256) out_count[i] = (nc_s[i] + 1e-5f) * scale;
  __syncthreads();

  float ln = 0.f, lm = 0.f;
  for (int i = tid; i < 4096; i += 256) { ln += loss_part[i]; lm += mask_part[i]; }
  red[tid] = ln; __syncthreads();
  for (int s = 128; s > 0; s >>= 1) { if (tid < s) red[tid] += red[tid + s]; __syncthreads(); }
  ln = red[0]; __syncthreads();
  red[tid] = lm; __syncthreads();
  for (int s = 128; s > 0; s >>= 1) { if (tid < s) red[tid] += red[tid + s]; __syncthreads(); }
  lm = red[0];
  if (tid == 0) out_loss[0] = 2.5f * ln / lm;      // 10 * 0.25 * num/den
}

extern "C" void kernel_launch(void* const* d_in, const int* in_sizes, int n_in,
                              void* d_out, int out_size, void* d_ws, size_t ws_size,
                              hipStream_t stream) {
  const float* z          = (const float*)d_in[0];
  const float* mask       = (const float*)d_in[1];
  const float* codebook   = (const float*)d_in[2];
  const float* ema_count  = (const float*)d_in[3];
  const float* ema_weight = (const float*)d_in[4];

  float* out        = (float*)d_out;
  float* out0       = out;                         // 4194304
  float* out_idx    = out + 4194304;               // 16384
  float* out_loss   = out + 4210688;               // 1
  float* out_count  = out + 4210689;               // 4096
  float* out_weight = out + 4214785;               // 1048576

  char* ws = (char*)d_ws;
  unsigned short* zf  = (unsigned short*)(ws + WS_ZF);
  unsigned short* cp1 = (unsigned short*)(ws + WS_CP);
  float*  cn1    = (float*) (ws + WS_CN);
  float2* nrm    = (float2*)(ws + WS_NRM);
  float4* cand   = (float4*)(ws + WS_CAND);
  float*  dw     = (float*) (ws + WS_DW);
  float*  nacc   = (float*) (ws + WS_NACC);
  float*  nbmax  = (float*) (ws + WS_NB);
  float*  lpart  = (float*) (ws + WS_LPART);
  float*  mpart  = (float*) (ws + WS_MPART);

  (void)hipMemsetAsync(ws + WS_DW, 0, WS_ZERO_BYTES, stream);

  vq_split_z<<<2048, 256, 0, stream>>>(z, zf, nrm);
  vq_split_c<<<1024, 256, 0, stream>>>(codebook, cp1, cn1, nbmax);
  vq_scan<<<1024, 256, 0, stream>>>(zf, cp1, cn1, cand);
  vq_merge_scatter<<<4096, 256, 0, stream>>>(cand, z, mask, codebook, nrm, nbmax,
                                             out0, out_idx, dw, nacc, lpart, mpart);
  vq_finish_weight<<<1024, 256, 0, stream>>>(ema_weight, dw, out_weight);
  vq_finish_count<<<1, 256, 0, stream>>>(ema_count, nacc, lpart, mpart,
                                         out_count, out_loss);
}

// Round 7
// 167.160 us; speedup vs baseline: 1.9823x; 1.5295x over previous
//
#include <hip/hip_runtime.h>
#include <hip/hip_fp16.h>
#include <cstdint>
#include <cstddef>

// ---------------------------------------------------------------------------
// VectorQuantizerEMA on MI355X.  B=8,S=2048,D=256,K=4096 -> N=16384 tokens.
// R5 design: 32x32x16 MFMA scan with Z register-resident.
//   1) split z -> fp16 h1 fragments (B-operand layout) + per-token norms;
//      split codebook -> fp16 h1 rows + fp32 |c|^2 + per-block norm maxima
//      (R6: NO atomicMax chain; 1-block reduce kernel finishes nb[2])
//   2) vq_scan: grid = 128 token-groups x 8 entry-splits. Per block: 4 waves,
//      each wave owns 32 tokens (Z in 64 VGPRs), codebook streams via 16KB
//      dbuf LDS tiles (XOR-32 swizzle, staged with pre-swizzled global src).
//      Per 32-entry tile: 16 ds_read_b128 + 16 mfma_32x32x16_f16 + per-lane
//      running top-2. Output: 1 record/token/split -> 2MB.
//   3) vq_merge: min over 8 records, window = rigorous error bound, exact
//      fp64 rescore of windowed candidates; gather row -> out; loss partials;
//      distributed atomic scatter n/dw
//   4) new_weight elementwise; new_count normalize + loss finalize
// History: R1 removed same-address atomic chains in merge (429us). R2 dbuf
// (177us, util 25%). R3 counted-vmcnt: regressed. R4 1-GEMM+rescore (gemm
// 135us, merge bloated). R5 32x32 scan restructure (total 256us). R6: found
// vq_split_c's atomicMax chain = 96us (4096 waves x ~23ns same-address RMW,
// measured 96us) -- replaced with per-block partials + 1-block reduce.
// ---------------------------------------------------------------------------

#define N_TOK 16384
#define DIM   256
#define K_CB  4096

typedef _Float16 h8    __attribute__((ext_vector_type(8)));
typedef float    f32x4 __attribute__((ext_vector_type(4)));
typedef float    f32x16 __attribute__((ext_vector_type(16)));

// ---- ws layout (bytes) ----
#define WS_ZF      0u            // N_TOK * 512B fp16 frag layout = 8 MB
#define WS_CP      8388608u      // K_CB * 512B fp16 rows         = 2 MB
#define WS_CN      10485760u     // K_CB fp32 |c|^2               = 16 KB
#define WS_NRM     10502144u     // N_TOK float2                  = 128 KB
#define WS_CAND    10630144u     // N_TOK * 8 float4              = 2 MB
#define WS_DW      12727296u     // K_CB * DIM float              = 4 MB
#define WS_NACC    16921600u     // K_CB float                    = 16 KB
#define WS_NB      16937984u     // 2 floats (+pad 16B)
#define WS_LPART   16938000u     // 4096 float
#define WS_MPART   16954384u     // 4096 float
#define WS_NBPART  16970768u     // 1024 float2 = 8 KB
#define WS_ZERO_BYTES (4194304u + 16384u)         // DW + NACC only

__device__ __forceinline__ void gload_lds16(const void* g, void* l) {
  __builtin_amdgcn_global_load_lds(
      (const __attribute__((address_space(1))) uint32_t*)g,
      (__attribute__((address_space(3))) uint32_t*)l, 16, 0, 0);
}

// ---- 1a: split z -> fragment-layout fp16 + per-token norms -----------------
// zf layout: grp(tok>>7)*65536 + kt*4096 + (tok&127)*32 + h*16 bytes; chunk
// (kt,h) holds dims kt*16+h*8 .. +8 as 8 halves -> scan B-operand loads are
// perfectly coalesced (1KB per wave instruction).
__global__ void vq_split_z(const float* __restrict__ z, unsigned short* __restrict__ zf,
                           float2* __restrict__ nrm) {
  int t = blockIdx.x * 256 + threadIdx.x;       // 524288 threads, 32 per token
  int tok = t >> 5, c = t & 31;
  const float4* zp = reinterpret_cast<const float4*>(z) + (size_t)tok * 64 + c * 2;
  float4 va = zp[0], vb = zp[1];
  float x[8] = {va.x, va.y, va.z, va.w, vb.x, vb.y, vb.z, vb.w};
  union { _Float16 h[8]; uint4 u; } a;
  float s1 = 0.f, s2 = 0.f;
#pragma unroll
  for (int i = 0; i < 8; ++i) {
    _Float16 h1 = (_Float16)x[i];
    float lo = (x[i] - (float)h1) * 2048.0f;
    a.h[i] = h1;
    s1 += (float)h1 * (float)h1;
    s2 += lo * lo;
  }
  size_t off = (size_t)(tok >> 7) * 65536u + (size_t)(c >> 1) * 4096u
             + (size_t)(tok & 127) * 32u + (size_t)(c & 1) * 16u;
  *reinterpret_cast<uint4*>((unsigned char*)zf + off) = a.u;
#pragma unroll
  for (int o = 1; o < 32; o <<= 1) { s1 += __shfl_xor(s1, o); s2 += __shfl_xor(s2, o); }
  if (c == 0) nrm[tok] = make_float2(sqrtf(s1), sqrtf(s2));
}

// ---- 1b: split codebook -> h1 rows + |c|^2 + PER-BLOCK norm maxima ---------
__global__ void vq_split_c(const float* __restrict__ cb, unsigned short* __restrict__ cp1,
                           float* __restrict__ cn1, float2* __restrict__ nbpart) {
  __shared__ float sm1[4], sm2[4];
  int w = threadIdx.x >> 6, l = threadIdx.x & 63;
  int row = blockIdx.x * 4 + w;
  float4 v = reinterpret_cast<const float4*>(cb)[row * 64 + l];
  float x[4] = {v.x, v.y, v.z, v.w};
  union { _Float16 h[4]; ushort4 u; } a;
  double ss = 0.0;
  float s1 = 0.f, s2 = 0.f;
#pragma unroll
  for (int i = 0; i < 4; ++i) {
    _Float16 h1 = (_Float16)x[i];
    float lo = (x[i] - (float)h1) * 2048.0f;
    a.h[i] = h1;
    s1 += (float)h1 * (float)h1;
    s2 += lo * lo;
    ss += (double)x[i] * (double)x[i];
  }
  reinterpret_cast<ushort4*>(cp1)[row * 64 + l] = a.u;
  for (int off = 1; off < 64; off <<= 1) {
    s1 += __shfl_xor(s1, off); s2 += __shfl_xor(s2, off); ss += __shfl_xor(ss, off);
  }
  if (l == 0) {
    cn1[row] = (float)ss;
    sm1[w] = s1; sm2[w] = s2;
  }
  __syncthreads();
  if (threadIdx.x == 0) {
    float m1 = fmaxf(fmaxf(sm1[0], sm1[1]), fmaxf(sm1[2], sm1[3]));
    float m2 = fmaxf(fmaxf(sm2[0], sm2[1]), fmaxf(sm2[2], sm2[3]));
    nbpart[blockIdx.x] = make_float2(sqrtf(m1), sqrtf(m2));
  }
}

// ---- 1c: reduce 1024 per-block maxima -> nb[0..1] (1 block, no atomics) ----
__global__ void vq_nb_reduce(const float2* __restrict__ nbpart, float* __restrict__ nb) {
  __shared__ float r1[256], r2[256];
  int tid = threadIdx.x;
  float m1 = 0.f, m2 = 0.f;
  for (int i = tid; i < 1024; i += 256) {
    float2 p = nbpart[i];
    m1 = fmaxf(m1, p.x); m2 = fmaxf(m2, p.y);
  }
  r1[tid] = m1; r2[tid] = m2; __syncthreads();
  for (int s = 128; s > 0; s >>= 1) {
    if (tid < s) { r1[tid] = fmaxf(r1[tid], r1[tid + s]); r2[tid] = fmaxf(r2[tid], r2[tid + s]); }
    __syncthreads();
  }
  if (tid == 0) { nb[0] = r1[0]; nb[1] = r2[0]; }
}

// ---- 2: distance scan, 32x32x16 MFMA, per-lane running top-2 ---------------
// Grid 1024 = 128 token-groups x 8 entry-splits (XCD-swizzled). 4 waves/block,
// wave w owns tokens tok0+w*32..+31 (Z frags in 64 VGPRs). CB tile = 32
// entries x 512B in LDS, dbuf. Stored chunk = logical ^ (row&31) via
// pre-swizzled global SOURCE (gload_lds writes linearly).
// D = A(CB) x B(Z): col=lane&31 (token), row=(reg&3)+8*(reg>>2)+4*(lane>>5).
__global__ __launch_bounds__(256, 4) void vq_scan(
    const unsigned short* __restrict__ zf, const unsigned short* __restrict__ cp,
    const float* __restrict__ cn1, float4* __restrict__ cand) {
  __shared__ __align__(1024) unsigned char cbl[2][16384];
  __shared__ __align__(16) float cnl[2][32];

  const int bid  = blockIdx.x;
  const int wgid = (bid & 7) * 128 + (bid >> 3);   // bijective: 1024 = 8*128
  const int tg   = wgid >> 3;                      // 0..127 token group
  const int es   = wgid & 7;                       // 0..7 entry split
  const int tok0 = tg * 128;
  const int e0b  = es * 512;

  const int tx = threadIdx.x;
  const int w = tx >> 6, l = tx & 63;
  const int r = l & 31, h = l >> 5;

  // Z fragments (B-operand): 16 x h8 = 64 VGPRs, coalesced 1KB loads
  const unsigned char* zg = (const unsigned char*)zf + (size_t)tg * 65536u
                            + (unsigned)(w * 1024 + r * 32 + h * 16);
  h8 zfr[16];
#pragma unroll
  for (int kt = 0; kt < 16; ++kt)
    zfr[kt] = *reinterpret_cast<const h8*>(zg + kt * 4096);

  const unsigned char* cpb = (const unsigned char*)cp;

  float v1 = 3e38f, v2 = 3e38f;
  int   i1 = 0x7fffffff, i2 = 0x7fffffff;

  // prologue: stage tile 0 into buffer 0
#pragma unroll
  for (int j = 0; j < 4; ++j) {
    int row = (w * 4 + j) * 2 + h;                 // 0..31, each once
    int lc  = r ^ row;                             // logical chunk to fetch
    gload_lds16(cpb + (size_t)(e0b + row) * 512 + lc * 16,
                &cbl[0][(w * 4 + j) * 1024]);      // wave-uniform dst
  }
  if (tx < 8)
    gload_lds16((const unsigned char*)cn1 + (size_t)e0b * 4 + tx * 16, &cnl[0][0]);
  __syncthreads();

  for (int t = 0; t < 16; ++t) {
    const int b = t & 1;
    if (t < 15) {                                  // stage t+1 first
      const int e0n = e0b + (t + 1) * 32;
#pragma unroll
      for (int j = 0; j < 4; ++j) {
        int row = (w * 4 + j) * 2 + h;
        int lc  = r ^ row;
        gload_lds16(cpb + (size_t)(e0n + row) * 512 + lc * 16,
                    &cbl[b ^ 1][(w * 4 + j) * 1024]);
      }
      if (tx < 8)
        gload_lds16((const unsigned char*)cn1 + (size_t)e0n * 4 + tx * 16,
                    &cnl[b ^ 1][0]);
    }

    f32x16 acc;
#pragma unroll
    for (int i = 0; i < 16; ++i) acc[i] = 0.f;
#pragma unroll
    for (int kt = 0; kt < 16; ++kt) {
      int sc = (kt * 2 + h) ^ r;                   // swizzled chunk
      h8 af = *reinterpret_cast<const h8*>(&cbl[b][r * 512 + sc * 16]);
      acc = __builtin_amdgcn_mfma_f32_32x32x16_f16(af, zfr[kt], acc, 0, 0, 0);
    }

    const int e0 = e0b + t * 32 + 4 * h;
#pragma unroll
    for (int g = 0; g < 4; ++g) {
      f32x4 cnv = *reinterpret_cast<const f32x4*>(&cnl[b][g * 8 + 4 * h]);
#pragma unroll
      for (int q = 0; q < 4; ++q) {
        float d = cnv[q] - 2.0f * acc[g * 4 + q];
        int   e = e0 + g * 8 + q;
        bool c1 = d < v1, c2 = d < v2;
        i2 = c1 ? i1 : (c2 ? e : i2);
        v2 = c1 ? v1 : (c2 ? d : v2);
        i1 = c1 ? e : i1;
        v1 = c1 ? d : v1;
      }
    }
    __syncthreads();
  }

  // merge the two lane-halves (entries 4h split), then write one record
  {
    float ov1 = __shfl_xor(v1, 32), ov2 = __shfl_xor(v2, 32);
    int   oi1 = __shfl_xor(i1, 32), oi2 = __shfl_xor(i2, 32);
    if (ov1 < v1 || (ov1 == v1 && oi1 < i1)) {
      v2 = v1; i2 = i1; v1 = ov1; i1 = oi1;
    } else if (ov1 < v2 || (ov1 == v2 && oi1 < i2)) {
      v2 = ov1; i2 = oi1;
    }
    if (ov2 < v1 || (ov2 == v1 && oi2 < i1)) {
      v2 = v1; i2 = i1; v1 = ov2; i1 = oi2;
    } else if (ov2 < v2 || (ov2 == v2 && oi2 < i2)) {
      v2 = ov2; i2 = oi2;
    }
    if (h == 0) {
      int token = tok0 + w * 32 + r;
      cand[(size_t)token * 8 + es] =
          make_float4(v1, v2, __int_as_float(i1), __int_as_float(i2));
    }
  }
}

// ---- 3: window + exact fp64 rescore; out/loss; scatter n/dw ----------------
__global__ void vq_merge_scatter(
    const float4* __restrict__ cand, const float* __restrict__ z,
    const float* __restrict__ mask, const float* __restrict__ codebook,
    const float2* __restrict__ nrm, const float* __restrict__ nb,
    float* __restrict__ out0, float* __restrict__ out_idx,
    float* __restrict__ dw, float* __restrict__ nacc,
    float* __restrict__ loss_part, float* __restrict__ mask_part) {
  __shared__ float ls[4], ms[4];
  int w = threadIdx.x >> 6, l = threadIdx.x & 63;
  int token = blockIdx.x * 4 + w;

  float4 rec = cand[(size_t)token * 8 + (l & 7)];  // 8 records, replicated x8
  float rv1 = rec.x, rv2 = rec.y;
  int   ri1 = __float_as_int(rec.z), ri2 = __float_as_int(rec.w);
  float m_a = rv1;
  for (int o = 1; o < 8; o <<= 1) m_a = fminf(m_a, __shfl_xor(m_a, o));

  // rigorous error bound: z.c - h1.b1 = h1.e_c + e_z.b1 + e_z.e_c (scaled)
  float2 nh = nrm[token];
  float NB1 = nb[0], NB2 = nb[1];
  float E = 2.0f * ((nh.x * NB2 + nh.y * NB1) * (1.0f / 2048.0f)
                    + nh.y * NB2 * (1.0f / 4194304.0f));
  float thr = m_a + 2.0f * E * 1.05f + 0.05f;

  float4 zv = reinterpret_cast<const float4*>(z)[(size_t)token * 64 + l];

  unsigned long long c1 = __ballot((l < 8) && (rv1 <= thr));
  unsigned long long c2 = __ballot((l < 8) && (rv2 <= thr));
  double bd = 1e300; int bi = 0x7fffffff;
  while (c1 | c2) {
    int k;
    if (c1) { int s = __ffsll(c1) - 1; c1 &= c1 - 1; k = __shfl(ri1, s); }
    else    { int s = __ffsll(c2) - 1; c2 &= c2 - 1; k = __shfl(ri2, s); }
    float4 cv = reinterpret_cast<const float4*>(codebook)[(size_t)k * 64 + l];
    double d0 = (double)zv.x - cv.x, d1 = (double)zv.y - cv.y;
    double d2 = (double)zv.z - cv.z, d3 = (double)zv.w - cv.w;
    double dd = d0 * d0 + d1 * d1 + d2 * d2 + d3 * d3;
    for (int o = 1; o < 64; o <<= 1) dd += __shfl_xor(dd, o);
    if (dd < bd || (dd == bd && k < bi)) { bd = dd; bi = k; }
  }

  float4 cv = reinterpret_cast<const float4*>(codebook)[(size_t)bi * 64 + l];
  reinterpret_cast<float4*>(out0)[(size_t)token * 64 + l] = cv;   // quantized

  float mk = mask[token];
  if (l == 0) {
    out_idx[token] = (float)bi;
    ls[w] = mk * (float)bd * (1.0f / 256.0f);      // exact sum (z-q)^2
    ms[w] = mk;
    atomicAdd(&nacc[bi], mk);
  }
  if (mk != 0.0f) {
    float* p = dw + (size_t)bi * 256 + l * 4;
    atomicAdd(p + 0, mk * zv.x);
    atomicAdd(p + 1, mk * zv.y);
    atomicAdd(p + 2, mk * zv.z);
    atomicAdd(p + 3, mk * zv.w);
  }
  __syncthreads();
  if (threadIdx.x == 0) {
    loss_part[blockIdx.x] = ls[0] + ls[1] + ls[2] + ls[3];
    mask_part[blockIdx.x] = ms[0] + ms[1] + ms[2] + ms[3];
  }
}

// ---- 4a: new_weight --------------------------------------------------------
__global__ void vq_finish_weight(const float* __restrict__ ew, const float* __restrict__ dw,
                                 float* __restrict__ nw) {
  int i = blockIdx.x * 256 + threadIdx.x;          // over K*D/4
  float4 e = reinterpret_cast<const float4*>(ew)[i];
  float4 d = reinterpret_cast<const float4*>(dw)[i];
  float4 o;
  o.x = 0.99f * e.x + 0.01f * d.x;
  o.y = 0.99f * e.y + 0.01f * d.y;
  o.z = 0.99f * e.z + 0.01f * d.z;
  o.w = 0.99f * e.w + 0.01f * d.w;
  reinterpret_cast<float4*>(nw)[i] = o;
}

// ---- 4b: new_count normalize + deterministic loss reduce -------------------
__global__ void vq_finish_count(const float* __restrict__ ec, const float* __restrict__ nacc,
                                const float* __restrict__ loss_part,
                                const float* __restrict__ mask_part,
                                float* __restrict__ out_count, float* __restrict__ out_loss) {
  __shared__ float nc_s[K_CB];
  __shared__ float red[256];
  int tid = threadIdx.x;
  float part = 0.f;
  for (int i = tid; i < K_CB; i += 256) {
    float nc = 0.99f * ec[i] + 0.01f * nacc[i];
    nc_s[i] = nc; part += nc;
  }
  red[tid] = part; __syncthreads();
  for (int s = 128; s > 0; s >>= 1) { if (tid < s) red[tid] += red[tid + s]; __syncthreads(); }
  float total = red[0];
  float scale = total / (total + (float)K_CB * 1e-5f);
  for (int i = tid; i < K_CB; i += 256) out_count[i] = (nc_s[i] + 1e-5f) * scale;
  __syncthreads();

  float ln = 0.f, lm = 0.f;
  for (int i = tid; i < 4096; i += 256) { ln += loss_part[i]; lm += mask_part[i]; }
  red[tid] = ln; __syncthreads();
  for (int s = 128; s > 0; s >>= 1) { if (tid < s) red[tid] += red[tid + s]; __syncthreads(); }
  ln = red[0]; __syncthreads();
  red[tid] = lm; __syncthreads();
  for (int s = 128; s > 0; s >>= 1) { if (tid < s) red[tid] += red[tid + s]; __syncthreads(); }
  lm = red[0];
  if (tid == 0) out_loss[0] = 2.5f * ln / lm;      // 10 * 0.25 * num/den
}

extern "C" void kernel_launch(void* const* d_in, const int* in_sizes, int n_in,
                              void* d_out, int out_size, void* d_ws, size_t ws_size,
                              hipStream_t stream) {
  const float* z          = (const float*)d_in[0];
  const float* mask       = (const float*)d_in[1];
  const float* codebook   = (const float*)d_in[2];
  const float* ema_count  = (const float*)d_in[3];
  const float* ema_weight = (const float*)d_in[4];

  float* out        = (float*)d_out;
  float* out0       = out;                         // 4194304
  float* out_idx    = out + 4194304;               // 16384
  float* out_loss   = out + 4210688;               // 1
  float* out_count  = out + 4210689;               // 4096
  float* out_weight = out + 4214785;               // 1048576

  char* ws = (char*)d_ws;
  unsigned short* zf  = (unsigned short*)(ws + WS_ZF);
  unsigned short* cp1 = (unsigned short*)(ws + WS_CP);
  float*  cn1    = (float*) (ws + WS_CN);
  float2* nrm    = (float2*)(ws + WS_NRM);
  float4* cand   = (float4*)(ws + WS_CAND);
  float*  dw     = (float*) (ws + WS_DW);
  float*  nacc   = (float*) (ws + WS_NACC);
  float*  nbmax  = (float*) (ws + WS_NB);
  float*  lpart  = (float*) (ws + WS_LPART);
  float*  mpart  = (float*) (ws + WS_MPART);
  float2* nbpart = (float2*)(ws + WS_NBPART);

  (void)hipMemsetAsync(ws + WS_DW, 0, WS_ZERO_BYTES, stream);

  vq_split_z<<<2048, 256, 0, stream>>>(z, zf, nrm);
  vq_split_c<<<1024, 256, 0, stream>>>(codebook, cp1, cn1, nbpart);
  vq_nb_reduce<<<1, 256, 0, stream>>>(nbpart, nbmax);
  vq_scan<<<1024, 256, 0, stream>>>(zf, cp1, cn1, cand);
  vq_merge_scatter<<<4096, 256, 0, stream>>>(cand, z, mask, codebook, nrm, nbmax,
                                             out0, out_idx, dw, nacc, lpart, mpart);
  vq_finish_weight<<<1024, 256, 0, stream>>>(ema_weight, dw, out_weight);
  vq_finish_count<<<1, 256, 0, stream>>>(ema_count, nacc, lpart, mpart,
                                         out_count, out_loss);
}